// Round 7
// baseline (93.495 us; speedup 1.0000x reference)
//
#include <hip/hip_runtime.h>
#include <math.h>

// Problem constants (from reference)
#define BB 8
#define HH 1024
#define DD 4
#define TI 16            // i-rows per block
#define NJC 8            // j-chunks
#define JC (HH / NJC)    // 128 j per block
#define INV2PI 0.15915494309189535f

typedef float f32x2 __attribute__((ext_vector_type(2)));

// ws layout: float4 partial[NJC][BB][HH] = 1 MB

__global__ __launch_bounds__(256, 8) void kuramoto_partial(
    const float* __restrict__ theta, const float* __restrict__ A,
    const float* __restrict__ alpha, float* __restrict__ ws)
{
    const int blk = blockIdx.x;          // ((b*64 + it)*NJC + jc)
    const int jc  = blk & (NJC - 1);
    const int it  = (blk >> 3) & 63;
    const int b   = blk >> 9;
    const int i0  = it * TI;
    const int j0  = jc * JC;
    const int t   = threadIdx.x;
    const int ti  = t >> 4;              // 0..15
    const int tj  = t & 15;              // 0..15

    __shared__ float sTh[4][JC];         // theta_j planes (contiguous -> ds_read2 fusable)
    __shared__ float sAT[JC][TI + 1];    // A[b, j0+r, i0+c] transposed (8.7 KB)

    const float* Ab = A + (size_t)b * HH * HH;

    // stage theta_j SoA, pre-scaled to revolutions (threads 0..127, coalesced float4)
    if (t < JC) {
        const float4 v = ((const float4*)theta)[(size_t)b * HH + j0 + t];
        sTh[0][t] = v.x * INV2PI; sTh[1][t] = v.y * INV2PI;
        sTh[2][t] = v.z * INV2PI; sTh[3][t] = v.w * INV2PI;
    }

    // stage transposed A tile: 128 rows x 16 cols, coalesced float4 loads,
    // scalar LDS stores (stride 17: exactly 2 lanes/bank = free)
    {
        const int r = t >> 2;            // 0..63
        const int c = (t & 3) * 4;       // 0,4,8,12
        #pragma unroll
        for (int rr = 0; rr < JC; rr += 64) {
            const int row = rr + r;
            const float4 v = *(const float4*)&Ab[(size_t)(j0 + row) * HH + i0 + c];
            sAT[row][c + 0] = v.x;
            sAT[row][c + 1] = v.y;
            sAT[row][c + 2] = v.z;
            sAT[row][c + 3] = v.w;
        }
    }

    // theta_i in revolutions, packed in f32x2 pairs
    const float4 thi4 = ((const float4*)theta)[(size_t)b * HH + i0 + ti];
    const f32x2 thi01 = { thi4.x * INV2PI, thi4.y * INV2PI };
    const f32x2 thi23 = { thi4.z * INV2PI, thi4.w * INV2PI };

    __syncthreads();   // the only barrier

    const float4* Arow4  = (const float4*)(Ab    + (size_t)(i0 + ti) * HH + j0);
    const float4* alrow4 = (const float4*)(alpha + (size_t)(i0 + ti) * HH + j0);

    f32x2 acc01 = {0.f, 0.f};
    f32x2 acc23 = {0.f, 0.f};

    #pragma unroll
    for (int s = 0; s < JC / 64; ++s) {          // 2 iters, 4 j's each
        const int q = tj + 16 * s;
        const float4 ad = Arow4[q];              // coalesced dwordx4 (HBM stream)
        const float4 al = alrow4[q];             // coalesced dwordx4 (L3-resident)
        #pragma unroll
        for (int k = 0; k < 4; ++k) {
            const int j = 4 * q + k;
            // alat: 0.5 folded into finalize constant
            const float alat = fmaxf((&ad.x)[k] + sAT[j][ti], 0.0f);
            const float w    = (&al.x)[k] * INV2PI;       // alpha in revolutions
            const f32x2 w2   = { w, w };
            // LDS broadcasts (2-way alias = free); contiguous planes -> read2 fusable
            const f32x2 t01 = { sTh[0][j], sTh[1][j] };
            const f32x2 t23 = { sTh[2][j], sTh[3][j] };
            const f32x2 g01 = t01 - (thi01 + w2);         // v_pk_add_f32 x2
            const f32x2 g23 = t23 - (thi23 + w2);
            f32x2 s01, s23;
            s01.x = __builtin_amdgcn_sinf(g01.x);
            s01.y = __builtin_amdgcn_sinf(g01.y);
            s23.x = __builtin_amdgcn_sinf(g23.x);
            s23.y = __builtin_amdgcn_sinf(g23.y);
            const f32x2 alat2 = { alat, alat };
            acc01 += alat2 * s01;                          // v_pk_fma_f32
            acc23 += alat2 * s23;
        }
    }

    float a0 = acc01.x, a1 = acc01.y, a2 = acc23.x, a3 = acc23.y;

    // reduce over the 16 tj lanes (ti groups are lane-contiguous in a wave)
    #pragma unroll
    for (int off = 8; off >= 1; off >>= 1) {
        a0 += __shfl_down(a0, off, 16);
        a1 += __shfl_down(a1, off, 16);
        a2 += __shfl_down(a2, off, 16);
        a3 += __shfl_down(a3, off, 16);
    }

    if (tj == 0) {
        float4 r; r.x = a0; r.y = a1; r.z = a2; r.w = a3;
        ((float4*)ws)[((size_t)jc * BB + b) * HH + i0 + ti] = r;
    }
}

__global__ __launch_bounds__(256) void kuramoto_final(
    const float* __restrict__ theta, const float* __restrict__ gamma,
    const float* __restrict__ omega, const float* __restrict__ kappa,
    const float* __restrict__ ws, float* __restrict__ out)
{
    const int idx = blockIdx.x * 256 + threadIdx.x;   // (b,i) flat, 8192 total
    const int i   = idx & (HH - 1);
    const float4* w4 = (const float4*)ws;

    float4 p = w4[idx];
    #pragma unroll
    for (int jc = 1; jc < NJC; ++jc) {
        const float4 q = w4[(size_t)jc * BB * HH + idx];
        p.x += q.x; p.y += q.y; p.z += q.z; p.w += q.w;
    }

    const float4 th = ((const float4*)theta)[idx];
    const float4 om = ((const float4*)omega)[i];
    const float4 kp = ((const float4*)kappa)[i];
    const float  g  = gamma[idx];
    const float  inv = 0.5f / HH;   // K_COUP=1, DT=1, 0.5 from symmetrization fold

    float4 o;
    o.x = th.x + om.x + p.x * inv + kp.x * (g - th.x);
    o.y = th.y + om.y + p.y * inv + kp.y * (g - th.y);
    o.z = th.z + om.z + p.z * inv + kp.z * (g - th.z);
    o.w = th.w + om.w + p.w * inv + kp.w * (g - th.w);
    ((float4*)out)[idx] = o;
}

extern "C" void kernel_launch(void* const* d_in, const int* in_sizes, int n_in,
                              void* d_out, int out_size, void* d_ws, size_t ws_size,
                              hipStream_t stream) {
    const float* theta = (const float*)d_in[0];
    const float* gamma = (const float*)d_in[1];
    const float* A     = (const float*)d_in[2];
    const float* omega = (const float*)d_in[3];
    const float* kappa = (const float*)d_in[4];
    const float* alpha = (const float*)d_in[5];
    float* out = (float*)d_out;
    float* ws  = (float*)d_ws;

    hipLaunchKernelGGL(kuramoto_partial, dim3(BB * (HH / TI) * NJC), dim3(256), 0, stream,
                       theta, A, alpha, ws);
    hipLaunchKernelGGL(kuramoto_final, dim3(BB * HH / 256), dim3(256), 0, stream,
                       theta, gamma, omega, kappa, ws, out);
}